// Round 7
// baseline (225.347 us; speedup 1.0000x reference)
//
#include <hip/hip_runtime.h>

// 2-layer GAT forward, N nodes, K=16 neighbors (row-sorted, exactly 16/dst),
// feats 128 -> 64 -> 64, fp32 in/out.
//
// K1: h1 = x @ W1 (fp16 MFMA, A-single/W-dual) + scores    [persistent, prefetch]
// K2: attn(h1) -> xm (fp16)                                 [high-occ, pipelined]
// K3: h2 = xm @ W2 + scores                                 [persistent, B in regs]
// K4: attn(h2) -> out (fp32)
// De-fused on purpose: attention needs occupancy (latency-bound gathers),
// GEMM needs registers — R6 showed fusing them costs 13% occupancy and ~net 0.

typedef __attribute__((ext_vector_type(8))) _Float16 f16x8;
typedef __attribute__((ext_vector_type(4))) float floatx4;

static __device__ inline float ubitf(unsigned u) { union { unsigned u; float f; } v; v.u = u; return v.f; }
static __device__ inline unsigned fbitu(float f) { union { float f; unsigned u; } v; v.f = f; return v.u; }

// ---------------- K1: persistent gemm1 (X fp32 [n,128] @ W1 -> H fp16 + scores)
// 512 blocks x 4 waves; wave-strided 16-row tiles; X loads for tile t+1 issued
// while tile t runs MFMA (prefetch buffer converted to fp16 before reuse).
__global__ __launch_bounds__(256, 4) void gemm1_score(
    const float* __restrict__ X, const float* __restrict__ W,
    const float* __restrict__ av, _Float16* __restrict__ H,
    float* __restrict__ s1, float* __restrict__ s2, int n, int nwaves)
{
    constexpr int NKT = 4;                 // K = 128
    constexpr int NF = NKT * 4 * 64;
    __shared__ f16x8 Bhi[NF];
    __shared__ f16x8 Blo[NF];
    const int tid = threadIdx.x;

    for (int f = tid; f < NF; f += 256) {
        const int ln = f & 63, ntk = f >> 6;
        const int kt = ntk >> 2, nt = ntk & 3;
        const int kbase = kt * 32 + (ln >> 4) * 8;
        const int ccol = nt * 16 + (ln & 15);
        f16x8 hh, ll;
#pragma unroll
        for (int j = 0; j < 8; j++) {
            const float w = W[(kbase + j) * 64 + ccol];
            const _Float16 wh = (_Float16)w;
            hh[j] = wh;
            ll[j] = (_Float16)(w - (float)wh);
        }
        Bhi[f] = hh; Blo[f] = ll;
    }
    __syncthreads();

    const int wave_g = blockIdx.x * 4 + (tid >> 6);
    const int lane = tid & 63, quad = lane >> 4, l15 = lane & 15;
    const int ntiles = (n + 15) / 16;
    if (wave_g >= ntiles) return;

    float a1c[4], a2c[4];
#pragma unroll
    for (int nt = 0; nt < 4; nt++) {
        a1c[nt] = av[nt * 16 + l15];
        a2c[nt] = av[64 + nt * 16 + l15];
    }

    float4 nxt[2 * NKT];
    {
        int r = wave_g * 16 + l15; if (r > n - 1) r = n - 1;
        const float* xp = &X[(size_t)r * 128 + quad * 8];
#pragma unroll
        for (int kt = 0; kt < NKT; kt++) {
            nxt[2 * kt]     = *(const float4*)(xp + kt * 32);
            nxt[2 * kt + 1] = *(const float4*)(xp + kt * 32 + 4);
        }
    }

    for (int t = wave_g; t < ntiles; t += nwaves) {
        // convert prefetched raws to fp16 A-fragments, then reuse nxt for t+1
        f16x8 A[NKT];
#pragma unroll
        for (int kt = 0; kt < NKT; kt++) {
            f16x8 a;
            a[0] = (_Float16)nxt[2 * kt].x;     a[1] = (_Float16)nxt[2 * kt].y;
            a[2] = (_Float16)nxt[2 * kt].z;     a[3] = (_Float16)nxt[2 * kt].w;
            a[4] = (_Float16)nxt[2 * kt + 1].x; a[5] = (_Float16)nxt[2 * kt + 1].y;
            a[6] = (_Float16)nxt[2 * kt + 1].z; a[7] = (_Float16)nxt[2 * kt + 1].w;
            A[kt] = a;
        }
        const int tn = t + nwaves;
        if (tn < ntiles) {
            int r = tn * 16 + l15; if (r > n - 1) r = n - 1;
            const float* xp = &X[(size_t)r * 128 + quad * 8];
#pragma unroll
            for (int kt = 0; kt < NKT; kt++) {
                nxt[2 * kt]     = *(const float4*)(xp + kt * 32);
                nxt[2 * kt + 1] = *(const float4*)(xp + kt * 32 + 4);
            }
        }

        floatx4 acc[4] = {{0,0,0,0},{0,0,0,0},{0,0,0,0},{0,0,0,0}};
#pragma unroll
        for (int kt = 0; kt < NKT; kt++)
#pragma unroll
            for (int nt = 0; nt < 4; nt++) {
                const f16x8 bh = Bhi[(kt * 4 + nt) * 64 + lane];
                const f16x8 bl = Blo[(kt * 4 + nt) * 64 + lane];
                acc[nt] = __builtin_amdgcn_mfma_f32_16x16x32_f16(A[kt], bh, acc[nt], 0, 0, 0);
                acc[nt] = __builtin_amdgcn_mfma_f32_16x16x32_f16(A[kt], bl, acc[nt], 0, 0, 0);
            }

        // epilogue: C layout col=nt*16+l15, row=quad*4+reg
        float p1[4] = {0, 0, 0, 0}, p2[4] = {0, 0, 0, 0};
#pragma unroll
        for (int nt = 0; nt < 4; nt++)
#pragma unroll
            for (int reg = 0; reg < 4; reg++) {
                const int r = t * 16 + quad * 4 + reg;
                if (r < n) H[(size_t)r * 64 + nt * 16 + l15] = (_Float16)acc[nt][reg];
                p1[reg] = fmaf(acc[nt][reg], a1c[nt], p1[reg]);
                p2[reg] = fmaf(acc[nt][reg], a2c[nt], p2[reg]);
            }
#pragma unroll
        for (int m = 1; m < 16; m <<= 1)
#pragma unroll
            for (int reg = 0; reg < 4; reg++) {
                p1[reg] += __shfl_xor(p1[reg], m, 64);
                p2[reg] += __shfl_xor(p2[reg], m, 64);
            }
        if (l15 == 0)
#pragma unroll
            for (int reg = 0; reg < 4; reg++) {
                const int r = t * 16 + quad * 4 + reg;
                if (r < n) { s1[r] = p1[reg]; s2[r] = p2[reg]; }
            }
    }
}

// ---------------- K3: persistent gemm2 (Xm fp16 [n,64] @ W2), B in registers
__global__ __launch_bounds__(256, 4) void gemm2_score(
    const _Float16* __restrict__ Xm, const float* __restrict__ W,
    const float* __restrict__ av, _Float16* __restrict__ H,
    float* __restrict__ s1, float* __restrict__ s2, int n, int nwaves)
{
    constexpr int NKT = 2;                 // K = 64
    constexpr int NF = NKT * 4 * 64;       // 512
    __shared__ f16x8 Bhi[NF];
    __shared__ f16x8 Blo[NF];
    const int tid = threadIdx.x;

    for (int f = tid; f < NF; f += 256) {
        const int ln = f & 63, ntk = f >> 6;
        const int kt = ntk >> 2, nt = ntk & 3;
        const int kbase = kt * 32 + (ln >> 4) * 8;
        const int ccol = nt * 16 + (ln & 15);
        f16x8 hh, ll;
#pragma unroll
        for (int j = 0; j < 8; j++) {
            const float w = W[(kbase + j) * 64 + ccol];
            const _Float16 wh = (_Float16)w;
            hh[j] = wh;
            ll[j] = (_Float16)(w - (float)wh);
        }
        Bhi[f] = hh; Blo[f] = ll;
    }
    __syncthreads();

    const int lane = tid & 63, quad = lane >> 4, l15 = lane & 15;
    // whole B operand lives in registers: 16 x f16x8 = 64 VGPRs
    f16x8 bhr[NKT][4], blr[NKT][4];
#pragma unroll
    for (int kt = 0; kt < NKT; kt++)
#pragma unroll
        for (int nt = 0; nt < 4; nt++) {
            bhr[kt][nt] = Bhi[(kt * 4 + nt) * 64 + lane];
            blr[kt][nt] = Blo[(kt * 4 + nt) * 64 + lane];
        }

    const int wave_g = blockIdx.x * 4 + (tid >> 6);
    const int ntiles = (n + 15) / 16;
    if (wave_g >= ntiles) return;

    float a1c[4], a2c[4];
#pragma unroll
    for (int nt = 0; nt < 4; nt++) {
        a1c[nt] = av[nt * 16 + l15];
        a2c[nt] = av[64 + nt * 16 + l15];
    }

    f16x8 nxt[NKT];
    {
        int r = wave_g * 16 + l15; if (r > n - 1) r = n - 1;
        const _Float16* xp = &Xm[(size_t)r * 64 + quad * 8];
#pragma unroll
        for (int kt = 0; kt < NKT; kt++) nxt[kt] = *(const f16x8*)(xp + kt * 32);
    }

    for (int t = wave_g; t < ntiles; t += nwaves) {
        f16x8 A[NKT];
#pragma unroll
        for (int kt = 0; kt < NKT; kt++) A[kt] = nxt[kt];
        const int tn = t + nwaves;
        if (tn < ntiles) {
            int r = tn * 16 + l15; if (r > n - 1) r = n - 1;
            const _Float16* xp = &Xm[(size_t)r * 64 + quad * 8];
#pragma unroll
            for (int kt = 0; kt < NKT; kt++) nxt[kt] = *(const f16x8*)(xp + kt * 32);
        }

        floatx4 acc[4] = {{0,0,0,0},{0,0,0,0},{0,0,0,0},{0,0,0,0}};
#pragma unroll
        for (int kt = 0; kt < NKT; kt++)
#pragma unroll
            for (int nt = 0; nt < 4; nt++) {
                acc[nt] = __builtin_amdgcn_mfma_f32_16x16x32_f16(A[kt], bhr[kt][nt], acc[nt], 0, 0, 0);
                acc[nt] = __builtin_amdgcn_mfma_f32_16x16x32_f16(A[kt], blr[kt][nt], acc[nt], 0, 0, 0);
            }

        float p1[4] = {0, 0, 0, 0}, p2[4] = {0, 0, 0, 0};
#pragma unroll
        for (int nt = 0; nt < 4; nt++)
#pragma unroll
            for (int reg = 0; reg < 4; reg++) {
                const int r = t * 16 + quad * 4 + reg;
                if (r < n) H[(size_t)r * 64 + nt * 16 + l15] = (_Float16)acc[nt][reg];
                p1[reg] = fmaf(acc[nt][reg], a1c[nt], p1[reg]);
                p2[reg] = fmaf(acc[nt][reg], a2c[nt], p2[reg]);
            }
#pragma unroll
        for (int m = 1; m < 16; m <<= 1)
#pragma unroll
            for (int reg = 0; reg < 4; reg++) {
                p1[reg] += __shfl_xor(p1[reg], m, 64);
                p2[reg] += __shfl_xor(p2[reg], m, 64);
            }
        if (l15 == 0)
#pragma unroll
            for (int reg = 0; reg < 4; reg++) {
                const int r = t * 16 + quad * 4 + reg;
                if (r < n) { s1[r] = p1[reg]; s2[r] = p2[reg]; }
            }
    }
}

// ---------------- K2/K4: attention, 8 nodes/wave, 2-group software pipeline -
// lane = g*8+j (node g in [0,8), j in [0,8)); lane owns feats j*8..j*8+7.
// Pipeline: next group's col/s1 issued before current softmax; next s2 issued
// before consuming current gathers -> serial chain overlapped with the fmas.
template<typename OT>
__global__ __launch_bounds__(512, 4) void attn(
    const _Float16* __restrict__ H, const float* __restrict__ s1,
    const float* __restrict__ s2, const int* __restrict__ col,
    const float* __restrict__ bias, OT* __restrict__ out, int n, int nwaves)
{
    const int lane = threadIdx.x & 63;
    const int wave_g = blockIdx.x * 8 + (threadIdx.x >> 6);
    const int g = (lane >> 3) & 7, j = lane & 7;
    const int ngroups = (n + 7) / 8;
    if (wave_g >= ngroups) return;

    float bb[8];
    *(float4*)&bb[0] = *(const float4*)&bias[j * 8];
    *(float4*)&bb[4] = *(const float4*)&bias[j * 8 + 4];
    const int bb4 = (lane & 56) << 2;      // bpermute group-base byte index

    int t = wave_g;
    int dc = t * 8 + g; if (dc > n - 1) dc = n - 1;
    int c0 = col[dc * 16 + j];
    int c1 = col[dc * 16 + 8 + j];
    float s1d = s1[dc];
    float t20 = s2[c0], t21 = s2[c1];

    while (true) {
        const int tn = t + nwaves;
        int nc0 = 0, nc1 = 0; float ns1 = 0.0f;
        if (tn < ngroups) {                // issue next group's level-1 loads early
            int ndc = tn * 8 + g; if (ndc > n - 1) ndc = n - 1;
            nc0 = col[ndc * 16 + j];
            nc1 = col[ndc * 16 + 8 + j];
            ns1 = s1[ndc];
        }

        // softmax over the 16 edges of node (t*8+g)
        float e0 = s1d + t20, e1 = s1d + t21;
        e0 = (e0 > 0.0f) ? e0 : 0.2f * e0;
        e1 = (e1 > 0.0f) ? e1 : 0.2f * e1;
        float m = fmaxf(e0, e1);
        m = fmaxf(m, __shfl_xor(m, 1, 64));
        m = fmaxf(m, __shfl_xor(m, 2, 64));
        m = fmaxf(m, __shfl_xor(m, 4, 64));
        const float p0 = __expf(e0 - m), p1 = __expf(e1 - m);
        float s = p0 + p1;
        s += __shfl_xor(s, 1, 64); s += __shfl_xor(s, 2, 64); s += __shfl_xor(s, 4, 64);
        const float inv = 1.0f / s;
        const float att0 = p0 * inv, att1 = p1 * inv;

        int srck[16]; float attk[16];
#pragma unroll
        for (int k = 0; k < 8; k++) {
            srck[k]     = __builtin_amdgcn_ds_bpermute(bb4 + 4 * k, c0);
            srck[k + 8] = __builtin_amdgcn_ds_bpermute(bb4 + 4 * k, c1);
            attk[k]     = ubitf((unsigned)__builtin_amdgcn_ds_bpermute(bb4 + 4 * k, (int)fbitu(att0)));
            attk[k + 8] = ubitf((unsigned)__builtin_amdgcn_ds_bpermute(bb4 + 4 * k, (int)fbitu(att1)));
        }
        f16x8 hv[16];
#pragma unroll
        for (int k = 0; k < 16; k++)       // 16 gathers in flight (1 KB each)
            hv[k] = *(const f16x8*)&H[(size_t)srck[k] * 64 + j * 8];

        float nt20 = 0.0f, nt21 = 0.0f;
        if (tn < ngroups) { nt20 = s2[nc0]; nt21 = s2[nc1]; }   // next s2 in flight

        float acc[8] = {0, 0, 0, 0, 0, 0, 0, 0};
#pragma unroll
        for (int k = 0; k < 16; k++)       // consume gathers (overlaps next s2)
#pragma unroll
            for (int q = 0; q < 8; q++)
                acc[q] = fmaf(attk[k], (float)hv[k][q], acc[q]);

        const int dst = t * 8 + g;
        if (dst < n) {
            if constexpr (sizeof(OT) == 2) {
                f16x8 o;
#pragma unroll
                for (int q = 0; q < 8; q++)
                    o[q] = (_Float16)fmaxf(acc[q] + bb[q], 0.0f);
                *(f16x8*)&out[(size_t)dst * 64 + j * 8] = o;
            } else {
                float4 o0, o1;
                o0.x = fmaxf(acc[0] + bb[0], 0.0f); o0.y = fmaxf(acc[1] + bb[1], 0.0f);
                o0.z = fmaxf(acc[2] + bb[2], 0.0f); o0.w = fmaxf(acc[3] + bb[3], 0.0f);
                o1.x = fmaxf(acc[4] + bb[4], 0.0f); o1.y = fmaxf(acc[5] + bb[5], 0.0f);
                o1.z = fmaxf(acc[6] + bb[6], 0.0f); o1.w = fmaxf(acc[7] + bb[7], 0.0f);
                *(float4*)&out[(size_t)dst * 64 + j * 8] = o0;
                *(float4*)&out[(size_t)dst * 64 + j * 8 + 4] = o1;
            }
        }

        if (tn >= ngroups) break;
        t = tn; c0 = nc0; c1 = nc1; s1d = ns1; t20 = nt20; t21 = nt21;
    }
}

extern "C" void kernel_launch(void* const* d_in, const int* in_sizes, int n_in,
                              void* d_out, int out_size, void* d_ws, size_t ws_size,
                              hipStream_t stream)
{
    const float* x        = (const float*)d_in[0];
    const int*   edge_col = (const int*)  d_in[2];
    const float* W1       = (const float*)d_in[3];
    const float* a1       = (const float*)d_in[4];
    const float* b1       = (const float*)d_in[5];
    const float* W2       = (const float*)d_in[6];
    const float* a2       = (const float*)d_in[7];
    const float* b2       = (const float*)d_in[8];
    const int n = in_sizes[0] / 128;     // 100000

    _Float16* h1 = (_Float16*)d_ws;                  // n*64 fp16
    _Float16* xm = h1 + (size_t)n * 64;              // n*64 fp16
    _Float16* h2 = xm + (size_t)n * 64;              // n*64 fp16
    float* s1a = (float*)(h2 + (size_t)n * 64);      // n
    float* s2a = s1a + n;
    float* s1b = s2a + n;
    float* s2b = s1b + n;

    const int GB = 512;                              // 2 blocks/CU, persistent
    const int gemm_waves = GB * 4;
    const int AB = 782;                              // ~2 groups/wave
    const int attn_waves = AB * 8;

    gemm1_score<<<GB, 256, 0, stream>>>(x, W1, a1, h1, s1a, s2a, n, gemm_waves);
    attn<_Float16><<<AB, 512, 0, stream>>>(h1, s1a, s2a, edge_col, b1, xm, n, attn_waves);
    gemm2_score<<<GB, 256, 0, stream>>>(xm, W2, a2, h2, s1b, s2b, n, gemm_waves);
    attn<float><<<AB, 512, 0, stream>>>(h2, s1b, s2b, edge_col, b2, (float*)d_out, n, attn_waves);
}

// Round 8
// 184.284 us; speedup vs baseline: 1.2228x; 1.2228x over previous
//
#include <hip/hip_runtime.h>

// 2-layer GAT forward, N nodes, K=16 neighbors (row-sorted, exactly 16/dst),
// feats 128 -> 64 -> 64, fp32 in/out.
//
// K1: h1 = x @ W1 (fp16 MFMA, single-precision-W) + scores s1a,s2a
// K2: attn(h1) -> xm fp16            [4 nodes/wave, 28-VGPR, max occupancy]
// K3: h2 = xm @ W2 + scores          [B operand entirely in registers]
// K4: attn(h2) -> out fp32
//
// Numerics: fp16 A and W with fp32 MFMA accumulation. W-lo correction dropped
// (R8): W-quant error ~2e-3 max, same order as the A-side fp16 error; measured
// headroom at R5 was 5.8x the harness threshold.
// Structure notes (measured):
//  - R6: fusing attn+gemm cost occupancy (13%) -> net zero. Keep de-fused.
//  - R7: __launch_bounds__(256,4) strangled VGPRs -> serialized prefetch,
//    2.8x gemm regression. Keep (256,2) + 48-rows-upfront loads.

typedef __attribute__((ext_vector_type(8))) _Float16 f16x8;
typedef __attribute__((ext_vector_type(4))) _Float16 f16x4;
typedef __attribute__((ext_vector_type(4))) float floatx4;

static __device__ inline float ubitf(unsigned u) { union { unsigned u; float f; } v; v.u = u; return v.f; }
static __device__ inline unsigned fbitu(float f) { union { float f; unsigned u; } v; v.f = f; return v.u; }

// ---------------- K1: h1 = X(fp32)[n,128] @ W1 -> fp16 + scores -------------
// 4 waves x 48 rows (3 MFMA row-tiles); all X loads for the wave issued up
// front (24 KB in flight). B-frag f=(kt*4+nt)*64+lane holds
// B[k=kt*32+(lane>>4)*8+j][c=nt*16+(lane&15)].
template<int KD>
__global__ __launch_bounds__(256, 2) void gemm_score_f16(
    const float* __restrict__ X, const float* __restrict__ W,
    const float* __restrict__ av, _Float16* __restrict__ H,
    float* __restrict__ s1, float* __restrict__ s2, int n)
{
    constexpr int NKT = KD / 32;
    constexpr int NF = NKT * 4 * 64;
    __shared__ f16x8 Bs[NF];
    const int tid = threadIdx.x;

    for (int f = tid; f < NF; f += 256) {
        const int ln = f & 63, ntk = f >> 6;
        const int kt = ntk >> 2, nt = ntk & 3;
        const int kbase = kt * 32 + (ln >> 4) * 8;
        const int ccol = nt * 16 + (ln & 15);
        f16x8 hh;
#pragma unroll
        for (int j = 0; j < 8; j++)
            hh[j] = (_Float16)W[(kbase + j) * 64 + ccol];
        Bs[f] = hh;
    }
    __syncthreads();

    const int wave = tid >> 6, lane = tid & 63;
    const int quad = lane >> 4, l15 = lane & 15;
    const int r0 = blockIdx.x * 192 + wave * 48;

    float a1c[4], a2c[4];
#pragma unroll
    for (int nt = 0; nt < 4; nt++) {
        a1c[nt] = av[nt * 16 + l15];
        a2c[nt] = av[64 + nt * 16 + l15];
    }

    // prefetch all raw X for the wave's 48 rows (max loads in flight)
    float4 raw[NKT][3][2];
#pragma unroll
    for (int rb = 0; rb < 3; rb++) {
        int ra = r0 + rb * 16 + l15; if (ra > n - 1) ra = n - 1;
        const float* xp = &X[(size_t)ra * KD + quad * 8];
#pragma unroll
        for (int kt = 0; kt < NKT; kt++) {
            raw[kt][rb][0] = *(const float4*)(xp + kt * 32);
            raw[kt][rb][1] = *(const float4*)(xp + kt * 32 + 4);
        }
    }
    f16x8 A[NKT][3];
#pragma unroll
    for (int kt = 0; kt < NKT; kt++)
#pragma unroll
        for (int rb = 0; rb < 3; rb++) {
            f16x8 a;
            a[0] = (_Float16)raw[kt][rb][0].x; a[1] = (_Float16)raw[kt][rb][0].y;
            a[2] = (_Float16)raw[kt][rb][0].z; a[3] = (_Float16)raw[kt][rb][0].w;
            a[4] = (_Float16)raw[kt][rb][1].x; a[5] = (_Float16)raw[kt][rb][1].y;
            a[6] = (_Float16)raw[kt][rb][1].z; a[7] = (_Float16)raw[kt][rb][1].w;
            A[kt][rb] = a;
        }

    floatx4 acc[4][3];
#pragma unroll
    for (int nt = 0; nt < 4; nt++)
#pragma unroll
        for (int rb = 0; rb < 3; rb++) acc[nt][rb] = (floatx4){0, 0, 0, 0};

#pragma unroll
    for (int kt = 0; kt < NKT; kt++)
#pragma unroll
        for (int nt = 0; nt < 4; nt++) {
            const f16x8 b = Bs[(kt * 4 + nt) * 64 + lane];
#pragma unroll
            for (int rb = 0; rb < 3; rb++)
                acc[nt][rb] = __builtin_amdgcn_mfma_f32_16x16x32_f16(A[kt][rb], b, acc[nt][rb], 0, 0, 0);
        }

    // epilogue: C layout col=nt*16+l15, row=quad*4+reg
#pragma unroll
    for (int rb = 0; rb < 3; rb++) {
        float p1[4] = {0, 0, 0, 0}, p2[4] = {0, 0, 0, 0};
#pragma unroll
        for (int nt = 0; nt < 4; nt++)
#pragma unroll
            for (int reg = 0; reg < 4; reg++) {
                const int r = r0 + rb * 16 + quad * 4 + reg;
                if (r < n) H[(size_t)r * 64 + nt * 16 + l15] = (_Float16)acc[nt][rb][reg];
                p1[reg] = fmaf(acc[nt][rb][reg], a1c[nt], p1[reg]);
                p2[reg] = fmaf(acc[nt][rb][reg], a2c[nt], p2[reg]);
            }
#pragma unroll
        for (int m = 1; m < 16; m <<= 1)
#pragma unroll
            for (int reg = 0; reg < 4; reg++) {
                p1[reg] += __shfl_xor(p1[reg], m, 64);
                p2[reg] += __shfl_xor(p2[reg], m, 64);
            }
        if (l15 == 0)
#pragma unroll
            for (int reg = 0; reg < 4; reg++) {
                const int r = r0 + rb * 16 + quad * 4 + reg;
                if (r < n) { s1[r] = p1[reg]; s2[r] = p2[reg]; }
            }
    }
}

// ---------------- K3: h2 = Xm(fp16)[n,64] @ W2 -> fp16 + scores -------------
// B operand (8 fragments = 32 VGPR) hoisted to registers; loop body is just
// 6 b128 A-loads + 24 MFMA + epilogue.
__global__ __launch_bounds__(256, 2) void gemm2_score(
    const _Float16* __restrict__ Xm, const float* __restrict__ W,
    const float* __restrict__ av, _Float16* __restrict__ H,
    float* __restrict__ s1, float* __restrict__ s2, int n)
{
    constexpr int NKT = 2;                 // K = 64
    constexpr int NF = NKT * 4 * 64;       // 512 fragments (8 KB)
    __shared__ f16x8 Bs[NF];
    const int tid = threadIdx.x;

    for (int f = tid; f < NF; f += 256) {
        const int ln = f & 63, ntk = f >> 6;
        const int kt = ntk >> 2, nt = ntk & 3;
        const int kbase = kt * 32 + (ln >> 4) * 8;
        const int ccol = nt * 16 + (ln & 15);
        f16x8 hh;
#pragma unroll
        for (int j = 0; j < 8; j++)
            hh[j] = (_Float16)W[(kbase + j) * 64 + ccol];
        Bs[f] = hh;
    }
    __syncthreads();

    const int wave = tid >> 6, lane = tid & 63;
    const int quad = lane >> 4, l15 = lane & 15;
    const int r0 = blockIdx.x * 192 + wave * 48;

    f16x8 br[NKT][4];
#pragma unroll
    for (int kt = 0; kt < NKT; kt++)
#pragma unroll
        for (int nt = 0; nt < 4; nt++)
            br[kt][nt] = Bs[(kt * 4 + nt) * 64 + lane];

    float a1c[4], a2c[4];
#pragma unroll
    for (int nt = 0; nt < 4; nt++) {
        a1c[nt] = av[nt * 16 + l15];
        a2c[nt] = av[64 + nt * 16 + l15];
    }

    // all 6 A-fragment b128 loads issued up front
    f16x8 A[NKT][3];
#pragma unroll
    for (int rb = 0; rb < 3; rb++) {
        int ra = r0 + rb * 16 + l15; if (ra > n - 1) ra = n - 1;
        const _Float16* xp = &Xm[(size_t)ra * 64 + quad * 8];
#pragma unroll
        for (int kt = 0; kt < NKT; kt++)
            A[kt][rb] = *(const f16x8*)(xp + kt * 32);
    }

    floatx4 acc[4][3];
#pragma unroll
    for (int nt = 0; nt < 4; nt++)
#pragma unroll
        for (int rb = 0; rb < 3; rb++) acc[nt][rb] = (floatx4){0, 0, 0, 0};

#pragma unroll
    for (int kt = 0; kt < NKT; kt++)
#pragma unroll
        for (int nt = 0; nt < 4; nt++)
#pragma unroll
            for (int rb = 0; rb < 3; rb++)
                acc[nt][rb] = __builtin_amdgcn_mfma_f32_16x16x32_f16(A[kt][rb], br[kt][nt], acc[nt][rb], 0, 0, 0);

#pragma unroll
    for (int rb = 0; rb < 3; rb++) {
        float p1[4] = {0, 0, 0, 0}, p2[4] = {0, 0, 0, 0};
#pragma unroll
        for (int nt = 0; nt < 4; nt++)
#pragma unroll
            for (int reg = 0; reg < 4; reg++) {
                const int r = r0 + rb * 16 + quad * 4 + reg;
                if (r < n) H[(size_t)r * 64 + nt * 16 + l15] = (_Float16)acc[nt][rb][reg];
                p1[reg] = fmaf(acc[nt][rb][reg], a1c[nt], p1[reg]);
                p2[reg] = fmaf(acc[nt][rb][reg], a2c[nt], p2[reg]);
            }
#pragma unroll
        for (int m = 1; m < 16; m <<= 1)
#pragma unroll
            for (int reg = 0; reg < 4; reg++) {
                p1[reg] += __shfl_xor(p1[reg], m, 64);
                p2[reg] += __shfl_xor(p2[reg], m, 64);
            }
        if (l15 == 0)
#pragma unroll
            for (int reg = 0; reg < 4; reg++) {
                const int r = r0 + rb * 16 + quad * 4 + reg;
                if (r < n) { s1[r] = p1[reg]; s2[r] = p2[reg]; }
            }
    }
}

// ---------------- K2/K4: attention, 4 nodes/wave, 16 lanes/node -------------
// lane = g*16+j; lane owns feats j*4..j*4+3; f16x4 gathers (8B/lane ->
// 512B/instr). 28 VGPR -> max occupancy; memory-latency-bound by design.
template<typename OT>
__global__ __launch_bounds__(512) void attn(
    const _Float16* __restrict__ H, const float* __restrict__ s1,
    const float* __restrict__ s2, const int* __restrict__ col,
    const float* __restrict__ bias, OT* __restrict__ out, int n)
{
    const int lane = threadIdx.x & 63;
    const int wv = threadIdx.x >> 6;
    const int j = lane & 15;
    const int dst = blockIdx.x * 32 + wv * 4 + (lane >> 4);
    if (dst >= n) return;

    const int c = col[dst * 16 + j];                 // coalesced
    float e = s1[dst] + s2[c];
    e = (e > 0.0f) ? e : 0.2f * e;                   // leaky_relu 0.2
    float m = e;
#pragma unroll
    for (int mk = 1; mk < 16; mk <<= 1) m = fmaxf(m, __shfl_xor(m, mk, 64));
    float p = __expf(e - m);
    float s = p;
#pragma unroll
    for (int mk = 1; mk < 16; mk <<= 1) s += __shfl_xor(s, mk, 64);
    const float att = p / s;

    const int bbase = (lane & 48) << 2;
    int srck[16]; float attk[16];
#pragma unroll
    for (int k = 0; k < 16; k++) {
        const int bidx = bbase + (k << 2);
        srck[k] = __builtin_amdgcn_ds_bpermute(bidx, c);
        attk[k] = ubitf((unsigned)__builtin_amdgcn_ds_bpermute(bidx, (int)fbitu(att)));
    }
    f16x4 hv[16];
#pragma unroll
    for (int k = 0; k < 16; k++)
        hv[k] = *(const f16x4*)&H[(size_t)srck[k] * 64 + j * 4];

    float a0 = 0, a1 = 0, a2 = 0, a3 = 0;
#pragma unroll
    for (int k = 0; k < 16; k++) {
        a0 = fmaf(attk[k], (float)hv[k][0], a0);
        a1 = fmaf(attk[k], (float)hv[k][1], a1);
        a2 = fmaf(attk[k], (float)hv[k][2], a2);
        a3 = fmaf(attk[k], (float)hv[k][3], a3);
    }
    const float4 bv = *(const float4*)&bias[j * 4];
    const float o0 = fmaxf(a0 + bv.x, 0.0f);
    const float o1 = fmaxf(a1 + bv.y, 0.0f);
    const float o2 = fmaxf(a2 + bv.z, 0.0f);
    const float o3 = fmaxf(a3 + bv.w, 0.0f);
    if constexpr (sizeof(OT) == 2) {
        f16x4 o; o[0] = (_Float16)o0; o[1] = (_Float16)o1;
                 o[2] = (_Float16)o2; o[3] = (_Float16)o3;
        *(f16x4*)&out[(size_t)dst * 64 + j * 4] = o;
    } else {
        float4 o; o.x = o0; o.y = o1; o.z = o2; o.w = o3;
        *(float4*)&out[(size_t)dst * 64 + j * 4] = o;
    }
}

extern "C" void kernel_launch(void* const* d_in, const int* in_sizes, int n_in,
                              void* d_out, int out_size, void* d_ws, size_t ws_size,
                              hipStream_t stream)
{
    const float* x        = (const float*)d_in[0];
    const int*   edge_col = (const int*)  d_in[2];
    const float* W1       = (const float*)d_in[3];
    const float* a1       = (const float*)d_in[4];
    const float* b1       = (const float*)d_in[5];
    const float* W2       = (const float*)d_in[6];
    const float* a2       = (const float*)d_in[7];
    const float* b2       = (const float*)d_in[8];
    const int n = in_sizes[0] / 128;     // 100000

    _Float16* h1 = (_Float16*)d_ws;                  // n*64 fp16
    _Float16* xm = h1 + (size_t)n * 64;              // n*64 fp16
    _Float16* h2 = xm + (size_t)n * 64;              // n*64 fp16
    float* s1a = (float*)(h2 + (size_t)n * 64);      // n
    float* s2a = s1a + n;
    float* s1b = s2a + n;
    float* s2b = s1b + n;

    const int gemm_blocks = (n + 191) / 192;         // 521
    const int agg_blocks  = (n + 31) / 32;           // 3125

    gemm_score_f16<128><<<gemm_blocks, 256, 0, stream>>>(x, W1, a1, h1, s1a, s2a, n);
    attn<_Float16><<<agg_blocks, 512, 0, stream>>>(h1, s1a, s2a, edge_col, b1, xm, n);
    gemm2_score<<<gemm_blocks, 256, 0, stream>>>(xm, W2, a2, h2, s1b, s2b, n);
    attn<float><<<agg_blocks, 512, 0, stream>>>(h2, s1b, s2b, edge_col, b2, (float*)d_out, n);
}